// Round 8
// baseline (581.709 us; speedup 1.0000x reference)
//
#include <hip/hip_runtime.h>
#include <stdint.h>

#define B   256
#define IU  8      // in_units (i)
#define JC  1152   // in_channels (j)
#define NN  10     // num_units (n)
#define UU  16     // unit_size (u)
#define NU  160    // NN*UU
#define JN  11520  // JC*NN
#define WROW 1280  // NN*UU*IU, floats per j in W

// ---- fused: blog += db/B; c = softmax_j(blog); db = 0 -------------------
__global__ void k_softmax_upd(float* __restrict__ blog, float* __restrict__ db,
                              float* __restrict__ c) {
    int n = blockIdx.x;           // 0..9
    int tid = threadIdx.x;        // 256
    float myv[5]; int cnt = 0;
    for (int j = tid; j < JC; j += 256) {
        float val = blog[j*NN + n] + db[j*NN + n] * (1.f / (float)B);
        blog[j*NN + n] = val;
        db[j*NN + n] = 0.f;       // self-zero for next k_uhat_db
        myv[cnt++] = val;
    }
    __shared__ float red[256];
    float m = -1e30f;
    for (int k = 0; k < cnt; ++k) m = fmaxf(m, myv[k]);
    red[tid] = m; __syncthreads();
    for (int s = 128; s > 0; s >>= 1) {
        if (tid < s) red[tid] = fmaxf(red[tid], red[tid+s]);
        __syncthreads();
    }
    m = red[0]; __syncthreads();
    float sum = 0.f;
    for (int k = 0; k < cnt; ++k) sum += __expf(myv[k] - m);
    red[tid] = sum; __syncthreads();
    for (int s = 128; s > 0; s >>= 1) {
        if (tid < s) red[tid] += red[tid+s];
        __syncthreads();
    }
    float inv = 1.f / red[0];
    cnt = 0;
    for (int j = tid; j < JC; j += 256)
        c[j*NN + n] = __expf(myv[cnt++] - m) * inv;
}

// ---------------- heavy pass 1: sbuf[b][n*16+u] += c*u_hat ----------------
// grid (36 j-tiles of 32, 32 b-tiles of 8), block 256 (4 waves).
// Wave w handles j's [w*8, w*8+8). Lane = dn*32 + u*2 + ih.
// Coalesced W loads (64 consecutive float4 per wave-load).
// NO cross-lane ops in the j-loop: each ih-half accumulates c*d_half;
// halves combined once in the epilogue (c distributes over the j-sum).
__global__ void __launch_bounds__(256, 2)
k_uhat_s(const float* __restrict__ xg, const float* __restrict__ wg,
         const float* __restrict__ cptr, float* __restrict__ sbuf) {
    const int j0 = blockIdx.x * 32, b0 = blockIdx.y * 8;
    const int tid   = threadIdx.x;
    const int wv_id = tid >> 6;
    const int lane  = tid & 63;
    const int dn = lane >> 5;
    const int u  = (lane >> 1) & 15;
    const int ih = lane & 1;

    __shared__ float xs[32 * 68];      // xs[jl*68 + b*8 + i]
    __shared__ float cs[320];          // cs[jl*10 + n]
    __shared__ float red[4 * 32 * 40]; // per-wave partials: 20 KB

    for (int idx = tid; idx < 2048; idx += 256) {
        int jl = idx & 31, r = idx >> 5, i = r & 7, b = r >> 3;
        xs[jl*68 + b*8 + i] = xg[(size_t)(b0 + b) * (IU*JC) + i * JC + j0 + jl];
    }
    if (cptr) for (int idx = tid; idx < 320; idx += 256) cs[idx] = cptr[j0*NN + idx];
    __syncthreads();

    float acc[40];                     // acc[b*5 + np], per-ih-half partial
    #pragma unroll
    for (int k = 0; k < 40; ++k) acc[k] = 0.f;

    for (int jj = 0; jj < 8; ++jj) {
        const int jl = wv_id * 8 + jj;
        const int j  = j0 + jl;
        const float4* wp = reinterpret_cast<const float4*>(wg + (size_t)j * WROW) + lane;
        float4 wv[5];
        #pragma unroll
        for (int np = 0; np < 5; ++np) wv[np] = wp[np * 64];   // coalesced 1KB/instr
        float cc[5];
        #pragma unroll
        for (int np = 0; np < 5; ++np)
            cc[np] = cptr ? cs[jl*NN + np*2 + dn] : (1.0f / (float)JC);
        float4 xr[8];
        #pragma unroll
        for (int b = 0; b < 8; ++b)
            xr[b] = *reinterpret_cast<const float4*>(&xs[jl*68 + b*8 + ih*4]);

        #pragma unroll
        for (int np = 0; np < 5; ++np) {
            float4 w = wv[np];
            #pragma unroll
            for (int b = 0; b < 8; ++b) {
                float4 xx = xr[b];
                float d = w.x * xx.x;
                d = fmaf(w.y, xx.y, d);
                d = fmaf(w.z, xx.z, d);
                d = fmaf(w.w, xx.w, d);
                acc[b*5 + np] = fmaf(d, cc[np], acc[b*5 + np]);  // no shfl here
            }
        }
    }

    // combine ih halves once
    #pragma unroll
    for (int k = 0; k < 40; ++k) acc[k] += __shfl_xor(acc[k], 1);

    // cross-wave reduce via LDS (ih==0 lanes hold the full value)
    if (ih == 0) {
        float* dst = &red[(size_t)(wv_id*32 + dn*16 + u) * 40];
        #pragma unroll
        for (int k = 0; k < 40; k += 4) {
            float4 t = make_float4(acc[k], acc[k+1], acc[k+2], acc[k+3]);
            *reinterpret_cast<float4*>(&dst[k]) = t;
        }
    }
    __syncthreads();
    #pragma unroll
    for (int q = 0; q < 5; ++q) {
        int tgt   = tid * 5 + q;     // 0..1279
        int combo = tgt / 40;        // dn*16 + u
        int k     = tgt % 40;        // b*5 + np
        float s = red[(0*32 + combo)*40 + k] + red[(1*32 + combo)*40 + k]
                + red[(2*32 + combo)*40 + k] + red[(3*32 + combo)*40 + k];
        int b = k / 5, np = k % 5;
        int dn2 = combo >> 4, u2 = combo & 15;
        atomicAdd(&sbuf[(size_t)(b0 + b) * NU + (np*2 + dn2)*16 + u2], s);
    }
}

// ---------------- squash: vdst[b][t] = squash(sbuf)[b][t]; sbuf = 0 ------
__global__ void k_reduce_s(float* __restrict__ sbuf, float* __restrict__ vdst) {
    int b = blockIdx.x, t = threadIdx.x;   // 160 threads: t = n*16+u
    float s = sbuf[(size_t)b * NU + t];
    sbuf[(size_t)b * NU + t] = 0.f;        // self-zero for next k_uhat_s
    __shared__ float sv[NU];
    __shared__ float fb[UU];
    sv[t] = s; __syncthreads();
    if (t < UU) {
        float m = 0.f;
        #pragma unroll
        for (int n = 0; n < NN; ++n) { float z = sv[n*16 + t]; m = fmaf(z, z, m); }
        fb[t] = sqrtf(m) / (1.f + m);   // == (m/(1+m)) / sqrt(m)
    }
    __syncthreads();
    vdst[(size_t)b * NU + t] = s * fb[t & 15];
}

// ---------------- heavy pass 2: db[j*10+n] += <u_hat, v> -----------------
// Same lane mapping & coalesced W loads. ZERO cross-lane ops in the j-loop:
// per-j scalars held in acc_t[8*5]; all reduction trees in the epilogue.
__global__ void __launch_bounds__(256, 2)
k_uhat_db(const float* __restrict__ xg, const float* __restrict__ wg,
          const float* __restrict__ v, float* __restrict__ db) {
    const int j0 = blockIdx.x * 32, b0 = blockIdx.y * 8;
    const int tid   = threadIdx.x;
    const int wv_id = tid >> 6;
    const int lane  = tid & 63;
    const int dn = lane >> 5;
    const int u  = (lane >> 1) & 15;
    const int ih = lane & 1;

    __shared__ float xs[32 * 68];
    __shared__ float vs2[8 * NU];

    for (int idx = tid; idx < 2048; idx += 256) {
        int jl = idx & 31, r = idx >> 5, i = r & 7, b = r >> 3;
        xs[jl*68 + b*8 + i] = xg[(size_t)(b0 + b) * (IU*JC) + i * JC + j0 + jl];
    }
    for (int idx = tid; idx < 8*NU; idx += 256)
        vs2[idx] = v[(size_t)b0 * NU + idx];
    __syncthreads();

    float vr[40];                       // vr[b*5 + np] = v[b][np*2+dn][u]
    #pragma unroll
    for (int b = 0; b < 8; ++b)
        #pragma unroll
        for (int np = 0; np < 5; ++np)
            vr[b*5 + np] = vs2[b*NU + (np*2 + dn)*16 + u];

    float acc_t[40];                    // acc_t[jj*5 + np]
    #pragma unroll
    for (int k = 0; k < 40; ++k) acc_t[k] = 0.f;

    for (int jj = 0; jj < 8; ++jj) {
        const int jl = wv_id * 8 + jj;
        const int j  = j0 + jl;
        const float4* wp = reinterpret_cast<const float4*>(wg + (size_t)j * WROW) + lane;
        float4 wv[5];
        #pragma unroll
        for (int np = 0; np < 5; ++np) wv[np] = wp[np * 64];
        float4 xr[8];
        #pragma unroll
        for (int b = 0; b < 8; ++b)
            xr[b] = *reinterpret_cast<const float4*>(&xs[jl*68 + b*8 + ih*4]);

        #pragma unroll
        for (int np = 0; np < 5; ++np) {
            float4 w = wv[np];
            float t = 0.f;
            #pragma unroll
            for (int b = 0; b < 8; ++b) {
                float4 xx = xr[b];
                float d = w.x * xx.x;
                d = fmaf(w.y, xx.y, d);
                d = fmaf(w.z, xx.z, d);
                d = fmaf(w.w, xx.w, d);
                t = fmaf(d, vr[b*5 + np], t);
            }
            acc_t[jj*5 + np] = t;
        }
    }

    // epilogue: reduce each (j, np) over lanes (ih + u bits) and commit
    #pragma unroll
    for (int jj = 0; jj < 8; ++jj) {
        #pragma unroll
        for (int np = 0; np < 5; ++np) {
            float t = acc_t[jj*5 + np];
            t += __shfl_xor(t, 1);
            t += __shfl_xor(t, 2);
            t += __shfl_xor(t, 4);
            t += __shfl_xor(t, 8);
            t += __shfl_xor(t, 16);
            if ((lane & 31) == 0)        // lanes 0 (dn=0), 32 (dn=1)
                atomicAdd(&db[(size_t)(j0 + wv_id*8 + jj) * NN + np*2 + dn], t);
        }
    }
}

extern "C" void kernel_launch(void* const* d_in, const int* in_sizes, int n_in,
                              void* d_out, int out_size, void* d_ws, size_t ws_size,
                              hipStream_t stream) {
    const float* x = (const float*)d_in[0];
    const float* w = (const float*)d_in[1];
    float* out = (float*)d_out;    // reference output dtype is float32

    float* ws   = (float*)d_ws;
    float* blog = ws;                 // 11520 floats
    float* c    = blog + JN;          // 11520
    float* sbuf = c + JN;             // 40960
    float* v    = sbuf + (size_t)B*NU;// 40960
    float* db   = v + (size_t)B*NU;   // 11520
    // total: 116480 floats = 465,920 bytes

    hipMemsetAsync(blog, 0, JN * sizeof(float), stream);
    hipMemsetAsync(sbuf, 0, (size_t)B * NU * sizeof(float), stream);
    hipMemsetAsync(db, 0, JN * sizeof(float), stream);

    for (int t = 0; t < 3; ++t) {
        // iter 0: c == softmax(0) == 1/JC exactly -> constant, no softmax launch
        k_uhat_s<<<dim3(36, 32), 256, 0, stream>>>(x, w, (t == 0) ? nullptr : c, sbuf);
        k_reduce_s<<<B, NU, 0, stream>>>(sbuf, (t == 2) ? out : v);
        if (t < 2) {
            k_uhat_db<<<dim3(36, 32), 256, 0, stream>>>(x, w, v, db);
            k_softmax_upd<<<NN, 256, 0, stream>>>(blog, db, c);
        }
    }
}

// Round 9
// 263.044 us; speedup vs baseline: 2.2114x; 2.2114x over previous
//
#include <hip/hip_runtime.h>
#include <stdint.h>

#define B   256
#define IU  8      // in_units (i)
#define JC  1152   // in_channels (j)
#define NN  10     // num_units (n)
#define UU  16     // unit_size (u)
#define NU  160    // NN*UU
#define JN  11520  // JC*NN
#define WROW 1280  // NN*UU*IU, floats per j in W

typedef short bf16x8 __attribute__((ext_vector_type(8)));
typedef float f32x4  __attribute__((ext_vector_type(4)));

__device__ __forceinline__ short f2bf(float f) {
    union { float f; uint32_t u; } cv; cv.f = f;
    uint32_t u = cv.u;
    uint32_t r = u + 0x7fffu + ((u >> 16) & 1u);
    return (short)(r >> 16);
}

// ---- fused: blog += db/B; c = softmax_j(blog); db = 0 -------------------
__global__ void k_softmax_upd(float* __restrict__ blog, float* __restrict__ db,
                              float* __restrict__ c) {
    int n = blockIdx.x;           // 0..9
    int tid = threadIdx.x;        // 256
    float myv[5]; int cnt = 0;
    for (int j = tid; j < JC; j += 256) {
        float val = blog[j*NN + n] + db[j*NN + n] * (1.f / (float)B);
        blog[j*NN + n] = val;
        db[j*NN + n] = 0.f;
        myv[cnt++] = val;
    }
    __shared__ float red[256];
    float m = -1e30f;
    for (int k = 0; k < cnt; ++k) m = fmaxf(m, myv[k]);
    red[tid] = m; __syncthreads();
    for (int s = 128; s > 0; s >>= 1) {
        if (tid < s) red[tid] = fmaxf(red[tid], red[tid+s]);
        __syncthreads();
    }
    m = red[0]; __syncthreads();
    float sum = 0.f;
    for (int k = 0; k < cnt; ++k) sum += __expf(myv[k] - m);
    red[tid] = sum; __syncthreads();
    for (int s = 128; s > 0; s >>= 1) {
        if (tid < s) red[tid] += red[tid+s];
        __syncthreads();
    }
    float inv = 1.f / red[0];
    cnt = 0;
    for (int j = tid; j < JC; j += 256)
        c[j*NN + n] = __expf(myv[cnt++] - m) * inv;
}

// ---------------- pass 1 as MFMA GEMM: s = x[256,9216] * (c*W)^T ---------
// k = j*8 + i. grid (KB k-splits, 4 m-tiles of 64 b). block 256 = 4 waves.
// Wave wv: C-tile = b[mb*64+wv*16 .. +16) x nu[0..160) as 10 MFMA frags.
// Per 16-j chunk: stage As[jj][b][i] (x, bf16), Bs[jj][nu][i] (c*W, bf16),
// then 4 k-steps x 10 mfma_f32_16x16x32_bf16.
// Commit: frag-ordered partials s_part[kb*4+mb][nt][tid][r] (reduce unpermutes).
__global__ void __launch_bounds__(256, 2)
k_gemm1(const float* __restrict__ xg, const float* __restrict__ wg,
        const float* __restrict__ cptr, float* __restrict__ s_part,
        int nchunks) {
    const int kb = blockIdx.x, mb = blockIdx.y;
    const int tid = threadIdx.x;
    const int wv = tid >> 6, lane = tid & 63;
    const int q = lane >> 4, l16 = lane & 15;
    const int b0 = mb * 64;
    const int jb0 = kb * (nchunks * 16);

    __shared__ __align__(16) short As[16 * 64 * 8];   // 16 KB
    __shared__ __align__(16) short Bs[16 * 160 * 8];  // 40 KB

    f32x4 acc[10];
    #pragma unroll
    for (int nt = 0; nt < 10; ++nt) acc[nt] = (f32x4){0.f, 0.f, 0.f, 0.f};

    for (int jc = 0; jc < nchunks; ++jc) {
        const int j0 = jb0 + jc * 16;
        __syncthreads();
        // stage As: x[b0+b][i][j0+jj] -> As[jj][b][i]
        #pragma unroll
        for (int p = 0; p < 8; ++p) {
            int idx = tid + 256 * p;       // 0..2047
            int row = idx >> 2;            // b*8+i
            int c4  = idx & 3;
            int bb = row >> 3, ii = row & 7;
            const float4 xv = *reinterpret_cast<const float4*>(
                &xg[(size_t)(b0 + bb) * (IU*JC) + ii * JC + j0 + c4*4]);
            int jjb = c4 * 4;
            As[((jjb+0)*64 + bb)*8 + ii] = f2bf(xv.x);
            As[((jjb+1)*64 + bb)*8 + ii] = f2bf(xv.y);
            As[((jjb+2)*64 + bb)*8 + ii] = f2bf(xv.z);
            As[((jjb+3)*64 + bb)*8 + ii] = f2bf(xv.w);
        }
        // stage Bs: c[j,n] * W[j][nu][i] -> Bs[jj][nu][i]
        #pragma unroll
        for (int p = 0; p < 20; ++p) {
            int f4 = tid + 256 * p;        // 0..5119
            int jj = f4 / 320;
            int w4 = f4 - jj * 320;        // (nu, ihalf)
            int nu = w4 >> 1, ihv = w4 & 1;
            int j = j0 + jj;
            const float4 wvv = *reinterpret_cast<const float4*>(
                &wg[(size_t)j * WROW + (size_t)w4 * 4]);
            float cc = cptr ? cptr[j * NN + (nu >> 4)] : (1.0f / (float)JC);
            short* d = &Bs[((jj*160 + nu) << 3) + ihv*4];
            d[0] = f2bf(wvv.x * cc); d[1] = f2bf(wvv.y * cc);
            d[2] = f2bf(wvv.z * cc); d[3] = f2bf(wvv.w * cc);
        }
        __syncthreads();
        #pragma unroll
        for (int s = 0; s < 4; ++s) {
            int jj = s*4 + q;
            bf16x8 av = *reinterpret_cast<const bf16x8*>(&As[((jj*64 + wv*16 + l16) << 3)]);
            #pragma unroll
            for (int nt = 0; nt < 10; ++nt) {
                bf16x8 bv = *reinterpret_cast<const bf16x8*>(&Bs[((jj*160 + nt*16 + l16) << 3)]);
                acc[nt] = __builtin_amdgcn_mfma_f32_16x16x32_bf16(av, bv, acc[nt], 0, 0, 0);
            }
        }
    }
    float* dst = s_part + (size_t)(kb*4 + mb) * 10240;
    #pragma unroll
    for (int nt = 0; nt < 10; ++nt)
        *reinterpret_cast<float4*>(&dst[(nt*256 + tid)*4]) =
            make_float4(acc[nt][0], acc[nt][1], acc[nt][2], acc[nt][3]);
}

// ---------------- reduce KB k-split partials + squash --------------------
// s_part slice layout: [nt][stid][r] with stid = wv*64 + q*16 + n16,
// b = wv*16 + q*4 + r  (MFMA C/D: col=lane&15, row=(lane>>4)*4+reg).
__global__ void k_reduce_s(const float* __restrict__ s_part, float* __restrict__ vdst,
                           int KB) {
    int b = blockIdx.x, t = threadIdx.x;   // 160 threads: t = nu
    int mb = b >> 6, bl = b & 63;
    int wv = bl >> 4, qq = (bl >> 2) & 3, r = bl & 3;
    int nt = t >> 4, n16 = t & 15;
    int stid = wv*64 + qq*16 + n16;
    size_t base = (size_t)mb * 10240 + (size_t)(nt*256 + stid)*4 + r;
    float s = 0.f;
    for (int kb = 0; kb < KB; ++kb)
        s += s_part[base + (size_t)kb * 40960];

    __shared__ float sv[NU];
    __shared__ float fb[UU];
    sv[t] = s; __syncthreads();
    if (t < UU) {
        float m = 0.f;
        #pragma unroll
        for (int n = 0; n < NN; ++n) { float z = sv[n*16 + t]; m = fmaf(z, z, m); }
        fb[t] = sqrtf(m) / (1.f + m);   // == (m/(1+m)) / sqrt(m)
    }
    __syncthreads();
    vdst[(size_t)b * NU + t] = s * fb[t & 15];
}

// ---------------- pass 2: db[j,n] += <u_hat, v> (VALU, scalar-only loop) --
// grid (36 j-tiles of 32, 32 b-tiles of 8), block 256: lane = dn*32+u*2+ih.
// Coalesced W loads; ih-halves accumulate independently (distributivity);
// one 5-level shfl tree per (j,np); NO register arrays with dynamic indices.
__global__ void __launch_bounds__(256, 2)
k_uhat_db(const float* __restrict__ xg, const float* __restrict__ wg,
          const float* __restrict__ v, float* __restrict__ db) {
    const int j0 = blockIdx.x * 32, b0 = blockIdx.y * 8;
    const int tid   = threadIdx.x;
    const int wv_id = tid >> 6;
    const int lane  = tid & 63;
    const int dn = lane >> 5;
    const int u  = (lane >> 1) & 15;
    const int ih = lane & 1;

    __shared__ float xs[32 * 68];
    __shared__ float vs2[8 * NU];

    for (int idx = tid; idx < 2048; idx += 256) {
        int jl = idx & 31, r = idx >> 5, i = r & 7, b = r >> 3;
        xs[jl*68 + b*8 + i] = xg[(size_t)(b0 + b) * (IU*JC) + i * JC + j0 + jl];
    }
    for (int idx = tid; idx < 8*NU; idx += 256)
        vs2[idx] = v[(size_t)b0 * NU + idx];
    __syncthreads();

    float vr[40];                       // vr[b*5 + np] = v[b][np*2+dn][u]
    #pragma unroll
    for (int b = 0; b < 8; ++b)
        #pragma unroll
        for (int np = 0; np < 5; ++np)
            vr[b*5 + np] = vs2[b*NU + (np*2 + dn)*16 + u];

    for (int jj = 0; jj < 8; ++jj) {
        const int jl = wv_id * 8 + jj;
        const int j  = j0 + jl;
        const float4* wp = reinterpret_cast<const float4*>(wg + (size_t)j * WROW) + lane;
        float4 wf[5];
        #pragma unroll
        for (int np = 0; np < 5; ++np) wf[np] = wp[np * 64];
        float4 xr[8];
        #pragma unroll
        for (int b = 0; b < 8; ++b)
            xr[b] = *reinterpret_cast<const float4*>(&xs[jl*68 + b*8 + ih*4]);

        #pragma unroll
        for (int np = 0; np < 5; ++np) {
            float4 w = wf[np];
            float t = 0.f;
            #pragma unroll
            for (int b = 0; b < 8; ++b) {
                float4 xx = xr[b];
                float d = w.x * xx.x;
                d = fmaf(w.y, xx.y, d);
                d = fmaf(w.z, xx.z, d);
                d = fmaf(w.w, xx.w, d);
                t = fmaf(d, vr[b*5 + np], t);     // per-ih-half partial
            }
            t += __shfl_xor(t, 1);
            t += __shfl_xor(t, 2);
            t += __shfl_xor(t, 4);
            t += __shfl_xor(t, 8);
            t += __shfl_xor(t, 16);
            if ((lane & 31) == 0)
                atomicAdd(&db[(size_t)j * NN + np*2 + dn], t);
        }
    }
}

extern "C" void kernel_launch(void* const* d_in, const int* in_sizes, int n_in,
                              void* d_out, int out_size, void* d_ws, size_t ws_size,
                              hipStream_t stream) {
    const float* x = (const float*)d_in[0];
    const float* w = (const float*)d_in[1];
    float* out = (float*)d_out;

    float* ws     = (float*)d_ws;
    float* blog   = ws;                  // 11520
    float* c      = blog + JN;           // 11520
    float* db     = c + JN;              // 11520
    float* v      = db + JN;             // 40960
    float* s_part = v + (size_t)B*NU;    // KB*4*10240 floats

    // pick largest K-split whose partial buffer fits the workspace
    size_t base_floats = 3*(size_t)JN + (size_t)B*NU;
    int KB = 72;
    while (KB > 9 && (base_floats + (size_t)KB * 4 * 10240) * 4 > ws_size) KB >>= 1;
    int nchunks = 72 / KB;               // 16*nchunks j's per block

    hipMemsetAsync(blog, 0, JN * sizeof(float), stream);
    hipMemsetAsync(db,   0, JN * sizeof(float), stream);

    for (int t = 0; t < 3; ++t) {
        k_gemm1<<<dim3(KB, 4), 256, 0, stream>>>(x, w, (t == 0) ? nullptr : c,
                                                 s_part, nchunks);
        k_reduce_s<<<B, NU, 0, stream>>>(s_part, (t == 2) ? out : v, KB);
        if (t < 2) {
            k_uhat_db<<<dim3(36, 32), 256, 0, stream>>>(x, w, v, db);
            k_softmax_upd<<<NN, 256, 0, stream>>>(blog, db, c);
        }
    }
}

// Round 10
// 219.701 us; speedup vs baseline: 2.6477x; 1.1973x over previous
//
#include <hip/hip_runtime.h>
#include <stdint.h>

#define B   256
#define IU  8      // in_units (i)
#define JC  1152   // in_channels (j)
#define NN  10     // num_units (n)
#define UU  16     // unit_size (u)
#define NU  160    // NN*UU
#define JN  11520  // JC*NN
#define WROW 1280  // NN*UU*IU, floats per j in W
#define NP  9216   // IU*JC, x row length (n' of the G-GEMM)

typedef short bf16x8 __attribute__((ext_vector_type(8)));
typedef float f32x4  __attribute__((ext_vector_type(4)));

__device__ __forceinline__ short f2bf(float f) {
    union { float f; uint32_t u; } cv; cv.f = f;
    uint32_t u = cv.u;
    uint32_t r = u + 0x7fffu + ((u >> 16) & 1u);
    return (short)(r >> 16);
}
__device__ __forceinline__ float bf2f(short h) {
    union { uint32_t u; float f; } cv; cv.u = ((uint32_t)(unsigned short)h) << 16;
    return cv.f;
}

// ---- fused: blog += db/B; c = softmax_j(blog) ---------------------------
__global__ void k_softmax_upd(float* __restrict__ blog, const float* __restrict__ db,
                              float* __restrict__ c) {
    int n = blockIdx.x;           // 0..9
    int tid = threadIdx.x;        // 256
    float myv[5]; int cnt = 0;
    for (int j = tid; j < JC; j += 256) {
        float val = blog[j*NN + n] + db[j*NN + n] * (1.f / (float)B);
        blog[j*NN + n] = val;
        myv[cnt++] = val;
    }
    __shared__ float red[256];
    float m = -1e30f;
    for (int k = 0; k < cnt; ++k) m = fmaxf(m, myv[k]);
    red[tid] = m; __syncthreads();
    for (int s = 128; s > 0; s >>= 1) {
        if (tid < s) red[tid] = fmaxf(red[tid], red[tid+s]);
        __syncthreads();
    }
    m = red[0]; __syncthreads();
    float sum = 0.f;
    for (int k = 0; k < cnt; ++k) sum += __expf(myv[k] - m);
    red[tid] = sum; __syncthreads();
    for (int s = 128; s > 0; s >>= 1) {
        if (tid < s) red[tid] += red[tid+s];
        __syncthreads();
    }
    float inv = 1.f / red[0];
    cnt = 0;
    for (int j = tid; j < JC; j += 256)
        c[j*NN + n] = __expf(myv[cnt++] - m) * inv;
}

// ---------------- pass 1 as MFMA GEMM: s = x[256,9216] * (c*W)^T ---------
__global__ void __launch_bounds__(256, 2)
k_gemm1(const float* __restrict__ xg, const float* __restrict__ wg,
        const float* __restrict__ cptr, float* __restrict__ s_part,
        int nchunks) {
    const int kb = blockIdx.x, mb = blockIdx.y;
    const int tid = threadIdx.x;
    const int wv = tid >> 6, lane = tid & 63;
    const int q = lane >> 4, l16 = lane & 15;
    const int b0 = mb * 64;
    const int jb0 = kb * (nchunks * 16);

    __shared__ __align__(16) short As[16 * 64 * 8];   // 16 KB
    __shared__ __align__(16) short Bs[16 * 160 * 8];  // 40 KB

    f32x4 acc[10];
    #pragma unroll
    for (int nt = 0; nt < 10; ++nt) acc[nt] = (f32x4){0.f, 0.f, 0.f, 0.f};

    for (int jc = 0; jc < nchunks; ++jc) {
        const int j0 = jb0 + jc * 16;
        __syncthreads();
        #pragma unroll
        for (int p = 0; p < 8; ++p) {
            int idx = tid + 256 * p;
            int row = idx >> 2;
            int c4  = idx & 3;
            int bb = row >> 3, ii = row & 7;
            const float4 xv = *reinterpret_cast<const float4*>(
                &xg[(size_t)(b0 + bb) * NP + ii * JC + j0 + c4*4]);
            int jjb = c4 * 4;
            As[((jjb+0)*64 + bb)*8 + ii] = f2bf(xv.x);
            As[((jjb+1)*64 + bb)*8 + ii] = f2bf(xv.y);
            As[((jjb+2)*64 + bb)*8 + ii] = f2bf(xv.z);
            As[((jjb+3)*64 + bb)*8 + ii] = f2bf(xv.w);
        }
        #pragma unroll
        for (int p = 0; p < 20; ++p) {
            int f4 = tid + 256 * p;
            int jj = f4 / 320;
            int w4 = f4 - jj * 320;
            int nu = w4 >> 1, ihv = w4 & 1;
            int j = j0 + jj;
            const float4 wvv = *reinterpret_cast<const float4*>(
                &wg[(size_t)j * WROW + (size_t)w4 * 4]);
            float cc = cptr ? cptr[j * NN + (nu >> 4)] : (1.0f / (float)JC);
            short* d = &Bs[((jj*160 + nu) << 3) + ihv*4];
            d[0] = f2bf(wvv.x * cc); d[1] = f2bf(wvv.y * cc);
            d[2] = f2bf(wvv.z * cc); d[3] = f2bf(wvv.w * cc);
        }
        __syncthreads();
        #pragma unroll
        for (int s = 0; s < 4; ++s) {
            int jj = s*4 + q;
            bf16x8 av = *reinterpret_cast<const bf16x8*>(&As[((jj*64 + wv*16 + l16) << 3)]);
            #pragma unroll
            for (int nt = 0; nt < 10; ++nt) {
                bf16x8 bv = *reinterpret_cast<const bf16x8*>(&Bs[((jj*160 + nt*16 + l16) << 3)]);
                acc[nt] = __builtin_amdgcn_mfma_f32_16x16x32_bf16(av, bv, acc[nt], 0, 0, 0);
            }
        }
    }
    float* dst = s_part + (size_t)(kb*4 + mb) * 10240;
    #pragma unroll
    for (int nt = 0; nt < 10; ++nt)
        *reinterpret_cast<float4*>(&dst[(nt*256 + tid)*4]) =
            make_float4(acc[nt][0], acc[nt][1], acc[nt][2], acc[nt][3]);
}

// ---------------- reduce KB k-split partials + squash --------------------
__global__ void k_reduce_s(const float* __restrict__ s_part, float* __restrict__ vdst,
                           int KB) {
    int b = blockIdx.x, t = threadIdx.x;   // 160 threads: t = nu
    int mb = b >> 6, bl = b & 63;
    int wv = bl >> 4, qq = (bl >> 2) & 3, r = bl & 3;
    int nt = t >> 4, n16 = t & 15;
    int stid = wv*64 + qq*16 + n16;
    size_t base = (size_t)mb * 10240 + (size_t)(nt*256 + stid)*4 + r;
    float s = 0.f;
    for (int kb = 0; kb < KB; ++kb)
        s += s_part[base + (size_t)kb * 40960];

    __shared__ float sv[NU];
    __shared__ float fb[UU];
    sv[t] = s; __syncthreads();
    if (t < UU) {
        float m = 0.f;
        #pragma unroll
        for (int n = 0; n < NN; ++n) { float z = sv[n*16 + t]; m = fmaf(z, z, m); }
        fb[t] = sqrtf(m) / (1.f + m);
    }
    __syncthreads();
    vdst[(size_t)b * NU + t] = s * fb[t & 15];
}

// ---------------- pass 2a: G[nu][n'] = sum_b v[b][nu] * x[b][n'] ---------
// Split-bf16 MFMA GEMM (M=160, N=9216, K=256): v=vh+vl, x=xh+xl,
// G = vh*xh + vh*xl + vl*xh (fp32-class accuracy).
// grid (144 n'-tiles of 64, 5 m-tiles of 32), block 256 = 4 waves.
// Wave wv: n'-sub = wv*16; acc: 2 m-frags. K-loop: 4 steps of 64 b.
__global__ void __launch_bounds__(256, 2)
k_vxg(const float* __restrict__ vg, const float* __restrict__ xg,
      float* __restrict__ G) {
    const int np0 = blockIdx.x * 64, m0 = blockIdx.y * 32;
    const int tid = threadIdx.x;
    const int wv = tid >> 6, lane = tid & 63;
    const int q = lane >> 4, l16 = lane & 15;

    __shared__ __align__(16) short Ash[8 * 32 * 8];  // 4 KB  [kc][ml][bi]
    __shared__ __align__(16) short Asl[8 * 32 * 8];
    __shared__ __align__(16) short Bsh[8 * 64 * 8];  // 8 KB  [kc][nl][bi]
    __shared__ __align__(16) short Bsl[8 * 64 * 8];

    f32x4 acc[2];
    acc[0] = (f32x4){0.f,0.f,0.f,0.f};
    acc[1] = (f32x4){0.f,0.f,0.f,0.f};

    for (int ks = 0; ks < 4; ++ks) {
        const int b0 = ks * 64;
        __syncthreads();
        // stage A (v slice): 64 b x 32 m
        #pragma unroll
        for (int p = 0; p < 8; ++p) {
            int idx = tid + 256 * p;            // 0..2047
            int bb = idx >> 5, ml = idx & 31;
            float vv = vg[(size_t)(b0 + bb) * NU + m0 + ml];
            short hi = f2bf(vv);
            short lo = f2bf(vv - bf2f(hi));
            int a = ((bb >> 3) * 32 + ml) * 8 + (bb & 7);
            Ash[a] = hi; Asl[a] = lo;
        }
        // stage B (x slice): 64 b x 64 n'
        #pragma unroll
        for (int p = 0; p < 16; ++p) {
            int idx = tid + 256 * p;            // 0..4095
            int bb = idx >> 6, nl = idx & 63;
            float xv = xg[(size_t)(b0 + bb) * NP + np0 + nl];
            short hi = f2bf(xv);
            short lo = f2bf(xv - bf2f(hi));
            int a = ((bb >> 3) * 64 + nl) * 8 + (bb & 7);
            Bsh[a] = hi; Bsl[a] = lo;
        }
        __syncthreads();
        #pragma unroll
        for (int s = 0; s < 2; ++s) {
            int kc = s*4 + q;
            bf16x8 bh = *reinterpret_cast<const bf16x8*>(&Bsh[((kc*64 + wv*16 + l16) << 3)]);
            bf16x8 bl = *reinterpret_cast<const bf16x8*>(&Bsl[((kc*64 + wv*16 + l16) << 3)]);
            #pragma unroll
            for (int mt = 0; mt < 2; ++mt) {
                bf16x8 ah = *reinterpret_cast<const bf16x8*>(&Ash[((kc*32 + mt*16 + l16) << 3)]);
                bf16x8 al = *reinterpret_cast<const bf16x8*>(&Asl[((kc*32 + mt*16 + l16) << 3)]);
                acc[mt] = __builtin_amdgcn_mfma_f32_16x16x32_bf16(ah, bh, acc[mt], 0, 0, 0);
                acc[mt] = __builtin_amdgcn_mfma_f32_16x16x32_bf16(ah, bl, acc[mt], 0, 0, 0);
                acc[mt] = __builtin_amdgcn_mfma_f32_16x16x32_bf16(al, bh, acc[mt], 0, 0, 0);
            }
        }
    }
    // C/D: col = lane&15 -> n'-local, row = q*4+reg -> m-local
    #pragma unroll
    for (int mt = 0; mt < 2; ++mt)
        #pragma unroll
        for (int reg = 0; reg < 4; ++reg) {
            int m  = m0 + mt*16 + q*4 + reg;
            G[(size_t)m * NP + np0 + wv*16 + l16] = acc[mt][reg];
        }
}

// ---------------- pass 2b: db[j,n] = sum_{u,i} W[j,n,u,i]*G[n*16+u][i*JC+j]
// grid (18 j-tiles of 64, 10 n), block 256: jl = tid&63, up = tid>>6.
// Thread: u in [up*4, up*4+4) x 8 i = 32 FMA; W per thread contiguous 32 floats;
// G reads coalesced across jl. LDS 4-way combine, direct db write (no atomics).
__global__ void k_wg_db(const float* __restrict__ wg, const float* __restrict__ G,
                        float* __restrict__ db) {
    const int j0 = blockIdx.x * 64, n = blockIdx.y;
    const int tid = threadIdx.x;
    const int jl = tid & 63, up = tid >> 6;
    const int j = j0 + jl;

    const float4* wp = reinterpret_cast<const float4*>(
        wg + (size_t)j * WROW + n * 128 + up * 32);
    float acc = 0.f;
    #pragma unroll
    for (int q4 = 0; q4 < 4; ++q4) {
        int u = up*4 + q4;
        const float* gp = G + (size_t)(n*16 + u) * NP + j;
        float4 w0 = wp[q4*2], w1 = wp[q4*2 + 1];
        acc = fmaf(w0.x, gp[0*JC], acc);
        acc = fmaf(w0.y, gp[1*JC], acc);
        acc = fmaf(w0.z, gp[2*JC], acc);
        acc = fmaf(w0.w, gp[3*JC], acc);
        acc = fmaf(w1.x, gp[4*JC], acc);
        acc = fmaf(w1.y, gp[5*JC], acc);
        acc = fmaf(w1.z, gp[6*JC], acc);
        acc = fmaf(w1.w, gp[7*JC], acc);
    }
    __shared__ float red[4][64];
    red[up][jl] = acc;
    __syncthreads();
    if (tid < 64)
        db[(size_t)(j0 + tid) * NN + n] =
            red[0][tid] + red[1][tid] + red[2][tid] + red[3][tid];
}

extern "C" void kernel_launch(void* const* d_in, const int* in_sizes, int n_in,
                              void* d_out, int out_size, void* d_ws, size_t ws_size,
                              hipStream_t stream) {
    const float* x = (const float*)d_in[0];
    const float* w = (const float*)d_in[1];
    float* out = (float*)d_out;

    float* ws     = (float*)d_ws;
    float* blog   = ws;                  // 11520
    float* c      = blog + JN;           // 11520
    float* db     = c + JN;              // 11520
    float* v      = db + JN;             // 40960
    float* arena  = v + (size_t)B*NU;    // union: s_part (KB*40960) / G (1474560)

    size_t base_floats = 3*(size_t)JN + (size_t)B*NU;   // 75,520
    int KB = 72;
    while (KB > 9) {
        size_t arena_f = (size_t)KB * 40960;
        if (arena_f < 1474560) arena_f = 1474560;
        if ((base_floats + arena_f) * 4 <= ws_size) break;
        KB >>= 1;
    }
    int nchunks = 72 / KB;
    float* s_part = arena;
    float* G      = arena;               // disjoint lifetimes within an iteration

    hipMemsetAsync(blog, 0, JN * sizeof(float), stream);

    for (int t = 0; t < 3; ++t) {
        k_gemm1<<<dim3(KB, 4), 256, 0, stream>>>(x, w, (t == 0) ? nullptr : c,
                                                 s_part, nchunks);
        k_reduce_s<<<B, NU, 0, stream>>>(s_part, (t == 2) ? out : v, KB);
        if (t < 2) {
            k_vxg<<<dim3(144, 5), 256, 0, stream>>>(v, x, G);
            k_wg_db<<<dim3(18, 10), 256, 0, stream>>>(w, G, db);
            k_softmax_upd<<<NN, 256, 0, stream>>>(blog, db, c);
        }
    }
}